// Round 3
// baseline (550.638 us; speedup 1.0000x reference)
//
#include <hip/hip_runtime.h>
#include <math.h>

#define BB 256
#define LL 512
#define DD 1024
#define NW 16    // waves per 1024-thread block
#define HT 256   // tokens per half-doc block

// ---------------------------------------------------------------------------
// Kernel 1: half-doc partial sums. Grid 512 = 2 blocks/doc = 2 blocks/CU
// (32 waves/CU => max occupancy for the random gather). Each wave sums 16
// rows in 4-row batches (16 float4 loads in flight).
// hpart[blk][d] = sum over 256 tokens of emb row.
// ---------------------------------------------------------------------------
__global__ __launch_bounds__(1024) void k_hidden(const int* __restrict__ tokens,
                                                 const float* __restrict__ emb,
                                                 float* __restrict__ hpart) {
    __shared__ int   toks[HT];
    __shared__ float part[NW][DD];   // 64 KB

    const int blk  = blockIdx.x;
    const int b    = blk >> 1;
    const int half = blk & 1;
    const int tid  = threadIdx.x;
    const int w    = tid >> 6;
    const int lane = tid & 63;
    const int off0 = lane * 4;

    if (tid < HT) toks[tid] = (tokens[b * LL + half * HT + tid] + 1) * DD;
    __syncthreads();

    float4 a0 = make_float4(0.f, 0.f, 0.f, 0.f);
    float4 a1 = a0, a2 = a0, a3 = a0;

    for (int i = 0; i < 16; i += 4) {
        const float* r0 = emb + toks[w * 16 + i + 0] + off0;
        const float* r1 = emb + toks[w * 16 + i + 1] + off0;
        const float* r2 = emb + toks[w * 16 + i + 2] + off0;
        const float* r3 = emb + toks[w * 16 + i + 3] + off0;

        const float4 e00 = *(const float4*)(r0      );
        const float4 e01 = *(const float4*)(r0 + 256);
        const float4 e02 = *(const float4*)(r0 + 512);
        const float4 e03 = *(const float4*)(r0 + 768);
        const float4 e10 = *(const float4*)(r1      );
        const float4 e11 = *(const float4*)(r1 + 256);
        const float4 e12 = *(const float4*)(r1 + 512);
        const float4 e13 = *(const float4*)(r1 + 768);
        const float4 e20 = *(const float4*)(r2      );
        const float4 e21 = *(const float4*)(r2 + 256);
        const float4 e22 = *(const float4*)(r2 + 512);
        const float4 e23 = *(const float4*)(r2 + 768);
        const float4 e30 = *(const float4*)(r3      );
        const float4 e31 = *(const float4*)(r3 + 256);
        const float4 e32 = *(const float4*)(r3 + 512);
        const float4 e33 = *(const float4*)(r3 + 768);

        a0.x += e00.x + e10.x + e20.x + e30.x;
        a0.y += e00.y + e10.y + e20.y + e30.y;
        a0.z += e00.z + e10.z + e20.z + e30.z;
        a0.w += e00.w + e10.w + e20.w + e30.w;
        a1.x += e01.x + e11.x + e21.x + e31.x;
        a1.y += e01.y + e11.y + e21.y + e31.y;
        a1.z += e01.z + e11.z + e21.z + e31.z;
        a1.w += e01.w + e11.w + e21.w + e31.w;
        a2.x += e02.x + e12.x + e22.x + e32.x;
        a2.y += e02.y + e12.y + e22.y + e32.y;
        a2.z += e02.z + e12.z + e22.z + e32.z;
        a2.w += e02.w + e12.w + e22.w + e32.w;
        a3.x += e03.x + e13.x + e23.x + e33.x;
        a3.y += e03.y + e13.y + e23.y + e33.y;
        a3.z += e03.z + e13.z + e23.z + e33.z;
        a3.w += e03.w + e13.w + e23.w + e33.w;
    }

    *(float4*)(&part[w][off0      ]) = a0;
    *(float4*)(&part[w][off0 + 256]) = a1;
    *(float4*)(&part[w][off0 + 512]) = a2;
    *(float4*)(&part[w][off0 + 768]) = a3;
    __syncthreads();

    float s = 0.f;
    #pragma unroll
    for (int j = 0; j < NW; ++j) s += part[j][tid];
    hpart[blk * DD + tid] = s;          // partial sum (scaled in k_q)
}

// ---------------------------------------------------------------------------
// Kernel 2: q[b,d] = sum_e W[d,e] * hidden[b,e]; hidden = (hp0+hp1)/L.
// grid (16, 64), 256 threads, 4 blocks/CU; W traffic 256 MB logical (L2-hot).
// ---------------------------------------------------------------------------
__global__ __launch_bounds__(256) void k_q(const float* __restrict__ hpart,
                                           const float* __restrict__ W,
                                           float* __restrict__ q) {
    __shared__ float hs[4][DD];
    const int dt  = blockIdx.x;   // 0..15
    const int bt  = blockIdx.y;   // 0..63
    const int tid = threadIdx.x;

    #pragma unroll
    for (int j = 0; j < 4; ++j) {
        const int doc = bt * 4 + j;
        #pragma unroll
        for (int k = 0; k < 4; ++k) {
            const int d = k * 256 + tid;
            hs[j][d] = (hpart[(2 * doc) * DD + d] + hpart[(2 * doc + 1) * DD + d])
                       * (1.0f / (float)LL);
        }
    }
    __syncthreads();

    const int w = tid >> 6, lane = tid & 63;

    for (int i = 0; i < 16; ++i) {
        const int d = dt * 64 + w * 16 + i;
        float a0 = 0.f, a1 = 0.f, a2 = 0.f, a3 = 0.f;
        #pragma unroll
        for (int k = 0; k < 4; ++k) {
            const int off = k * 256 + lane * 4;
            const float4 wv = *(const float4*)(W + (size_t)d * DD + off);
            const float4 h0 = *(const float4*)(&hs[0][off]);
            const float4 h1 = *(const float4*)(&hs[1][off]);
            const float4 h2 = *(const float4*)(&hs[2][off]);
            const float4 h3 = *(const float4*)(&hs[3][off]);
            a0 += wv.x * h0.x + wv.y * h0.y + wv.z * h0.z + wv.w * h0.w;
            a1 += wv.x * h1.x + wv.y * h1.y + wv.z * h1.z + wv.w * h1.w;
            a2 += wv.x * h2.x + wv.y * h2.y + wv.z * h2.z + wv.w * h2.w;
            a3 += wv.x * h3.x + wv.y * h3.y + wv.z * h3.z + wv.w * h3.w;
        }
        #pragma unroll
        for (int m = 32; m; m >>= 1) {
            a0 += __shfl_xor(a0, m, 64);
            a1 += __shfl_xor(a1, m, 64);
            a2 += __shfl_xor(a2, m, 64);
            a3 += __shfl_xor(a3, m, 64);
        }
        if (lane == 0) {
            q[(bt * 4 + 0) * DD + d] = a0;
            q[(bt * 4 + 1) * DD + d] = a1;
            q[(bt * 4 + 2) * DD + d] = a2;
            q[(bt * 4 + 3) * DD + d] = a3;
        }
    }
}

// ---------------------------------------------------------------------------
// Kernel 3: half-doc online softmax + context partial. Grid 512 = 2/CU.
// Per wave: 16 rows in 4-row batches (one rescale per 4 rows). Block merges
// its 16 wave-partials and writes unnormalized (ct, M, S) per half-doc.
// ---------------------------------------------------------------------------
__global__ __launch_bounds__(1024) void k_attn(const int* __restrict__ tokens,
                                               const float* __restrict__ emb,
                                               const float* __restrict__ q,
                                               float* __restrict__ cpart,
                                               float* __restrict__ mspart) {
    __shared__ int   toks[HT];
    __shared__ float ctp[NW][DD];   // 64 KB
    __shared__ float mw[NW], sw[NW];

    const int blk  = blockIdx.x;
    const int b    = blk >> 1;
    const int half = blk & 1;
    const int tid  = threadIdx.x;
    const int w    = tid >> 6;
    const int lane = tid & 63;
    const int off0 = lane * 4;

    if (tid < HT) toks[tid] = (tokens[b * LL + half * HT + tid] + 1) * DD;
    __syncthreads();

    const float4 q0 = *(const float4*)(q + b * DD + off0      );
    const float4 q1 = *(const float4*)(q + b * DD + off0 + 256);
    const float4 q2 = *(const float4*)(q + b * DD + off0 + 512);
    const float4 q3 = *(const float4*)(q + b * DD + off0 + 768);

    float m = -1e30f, s = 0.f;
    float4 c0 = make_float4(0.f, 0.f, 0.f, 0.f);
    float4 c1 = c0, c2 = c0, c3 = c0;

    for (int i = 0; i < 16; i += 4) {
        float4 e[4][4];
        #pragma unroll
        for (int r = 0; r < 4; ++r) {
            const float* rp = emb + toks[w * 16 + i + r] + off0;
            e[r][0] = *(const float4*)(rp      );
            e[r][1] = *(const float4*)(rp + 256);
            e[r][2] = *(const float4*)(rp + 512);
            e[r][3] = *(const float4*)(rp + 768);
        }

        float p[4];
        #pragma unroll
        for (int r = 0; r < 4; ++r) {
            p[r] = e[r][0].x*q0.x + e[r][0].y*q0.y + e[r][0].z*q0.z + e[r][0].w*q0.w
                 + e[r][1].x*q1.x + e[r][1].y*q1.y + e[r][1].z*q1.z + e[r][1].w*q1.w
                 + e[r][2].x*q2.x + e[r][2].y*q2.y + e[r][2].z*q2.z + e[r][2].w*q2.w
                 + e[r][3].x*q3.x + e[r][3].y*q3.y + e[r][3].z*q3.z + e[r][3].w*q3.w;
        }
        #pragma unroll
        for (int mm = 32; mm; mm >>= 1) {
            p[0] += __shfl_xor(p[0], mm, 64);
            p[1] += __shfl_xor(p[1], mm, 64);
            p[2] += __shfl_xor(p[2], mm, 64);
            p[3] += __shfl_xor(p[3], mm, 64);
        }

        const float nm = fmaxf(fmaxf(m, fmaxf(p[0], p[1])), fmaxf(p[2], p[3]));
        const float f  = __expf(m - nm);
        const float w0 = __expf(p[0] - nm);
        const float w1 = __expf(p[1] - nm);
        const float w2 = __expf(p[2] - nm);
        const float w3 = __expf(p[3] - nm);
        s = s * f + w0 + w1 + w2 + w3;

        c0.x = c0.x*f + w0*e[0][0].x + w1*e[1][0].x + w2*e[2][0].x + w3*e[3][0].x;
        c0.y = c0.y*f + w0*e[0][0].y + w1*e[1][0].y + w2*e[2][0].y + w3*e[3][0].y;
        c0.z = c0.z*f + w0*e[0][0].z + w1*e[1][0].z + w2*e[2][0].z + w3*e[3][0].z;
        c0.w = c0.w*f + w0*e[0][0].w + w1*e[1][0].w + w2*e[2][0].w + w3*e[3][0].w;
        c1.x = c1.x*f + w0*e[0][1].x + w1*e[1][1].x + w2*e[2][1].x + w3*e[3][1].x;
        c1.y = c1.y*f + w0*e[0][1].y + w1*e[1][1].y + w2*e[2][1].y + w3*e[3][1].y;
        c1.z = c1.z*f + w0*e[0][1].z + w1*e[1][1].z + w2*e[2][1].z + w3*e[3][1].z;
        c1.w = c1.w*f + w0*e[0][1].w + w1*e[1][1].w + w2*e[2][1].w + w3*e[3][1].w;
        c2.x = c2.x*f + w0*e[0][2].x + w1*e[1][2].x + w2*e[2][2].x + w3*e[3][2].x;
        c2.y = c2.y*f + w0*e[0][2].y + w1*e[1][2].y + w2*e[2][2].y + w3*e[3][2].y;
        c2.z = c2.z*f + w0*e[0][2].z + w1*e[1][2].z + w2*e[2][2].z + w3*e[3][2].z;
        c2.w = c2.w*f + w0*e[0][2].w + w1*e[1][2].w + w2*e[2][2].w + w3*e[3][2].w;
        c3.x = c3.x*f + w0*e[0][3].x + w1*e[1][3].x + w2*e[2][3].x + w3*e[3][3].x;
        c3.y = c3.y*f + w0*e[0][3].y + w1*e[1][3].y + w2*e[2][3].y + w3*e[3][3].y;
        c3.z = c3.z*f + w0*e[0][3].z + w1*e[1][3].z + w2*e[2][3].z + w3*e[3][3].z;
        c3.w = c3.w*f + w0*e[0][3].w + w1*e[1][3].w + w2*e[2][3].w + w3*e[3][3].w;
        m = nm;
    }

    *(float4*)(&ctp[w][off0      ]) = c0;
    *(float4*)(&ctp[w][off0 + 256]) = c1;
    *(float4*)(&ctp[w][off0 + 512]) = c2;
    *(float4*)(&ctp[w][off0 + 768]) = c3;
    if (lane == 0) { mw[w] = m; sw[w] = s; }
    __syncthreads();

    float M = -1e30f;
    #pragma unroll
    for (int j = 0; j < NW; ++j) M = fmaxf(M, mw[j]);
    float denom = 0.f, sc[NW];
    #pragma unroll
    for (int j = 0; j < NW; ++j) { sc[j] = __expf(mw[j] - M); denom += sc[j] * sw[j]; }

    float acc = 0.f;
    #pragma unroll
    for (int j = 0; j < NW; ++j) acc += sc[j] * ctp[j][tid];
    cpart[blk * DD + tid] = acc;                 // unnormalized, relative to M
    if (tid == 0) { mspart[blk * 2] = M; mspart[blk * 2 + 1] = denom; }
}

// ---------------------------------------------------------------------------
// Kernel 4: merge the two half-doc partials.
// ---------------------------------------------------------------------------
__global__ __launch_bounds__(1024) void k_merge(const float* __restrict__ cpart,
                                                const float* __restrict__ mspart,
                                                float* __restrict__ out) {
    const int b   = blockIdx.x;
    const int tid = threadIdx.x;
    const float M0 = mspart[(2 * b) * 2],     S0 = mspart[(2 * b) * 2 + 1];
    const float M1 = mspart[(2 * b + 1) * 2], S1 = mspart[(2 * b + 1) * 2 + 1];
    const float M  = fmaxf(M0, M1);
    const float f0 = __expf(M0 - M), f1 = __expf(M1 - M);
    const float inv = 1.0f / (f0 * S0 + f1 * S1);
    out[b * DD + tid] = (f0 * cpart[(2 * b) * DD + tid]
                       + f1 * cpart[(2 * b + 1) * DD + tid]) * inv;
}

// ---------------------------------------------------------------------------
extern "C" void kernel_launch(void* const* d_in, const int* in_sizes, int n_in,
                              void* d_out, int out_size, void* d_ws, size_t ws_size,
                              hipStream_t stream) {
    const int*   tokens = (const int*)d_in[0];
    // d_in[1] = max_len (scalar), fixed to LL
    const float* emb    = (const float*)d_in[2];
    const float* W      = (const float*)d_in[3];
    float*       out    = (float*)d_out;

    float* hpart  = (float*)d_ws;                 // 512*1024 floats = 2 MB
    float* q      = hpart  + 2 * BB * DD;         // 1 MB
    float* cpart  = q      + BB * DD;             // 2 MB
    float* mspart = cpart  + 2 * BB * DD;         // 2 KB

    k_hidden<<<BB * 2, 1024, 0, stream>>>(tokens, emb, hpart);
    dim3 g2(DD / 64, BB / 4);
    k_q<<<g2, 256, 0, stream>>>(hpart, W, q);
    k_attn<<<BB * 2, 1024, 0, stream>>>(tokens, emb, q, cpart, mspart);
    k_merge<<<BB, 1024, 0, stream>>>(cpart, mspart, out);
}

// Round 4
// 390.978 us; speedup vs baseline: 1.4084x; 1.4084x over previous
//
#include <hip/hip_runtime.h>
#include <hip/hip_fp16.h>
#include <math.h>

#define BB 256
#define LL 512
#define DD 1024
#define NW 16         // waves per 1024-thread block
#define VROWS 50001   // V+1 rows

// convert 8 halves packed in a float4 into 8 floats at dst[off..off+7]
#define CVT8(dst, off, v) { const __half2* hp2 = (const __half2*)&(v); float2 t; \
    t = __half22float2(hp2[0]); dst[(off)+0] = t.x; dst[(off)+1] = t.y; \
    t = __half22float2(hp2[1]); dst[(off)+2] = t.x; dst[(off)+3] = t.y; \
    t = __half22float2(hp2[2]); dst[(off)+4] = t.x; dst[(off)+5] = t.y; \
    t = __half22float2(hp2[3]); dst[(off)+6] = t.x; dst[(off)+7] = t.y; }

#define CVT8ADD(acc, off, v) { const __half2* hp2 = (const __half2*)&(v); float2 t; \
    t = __half22float2(hp2[0]); acc[(off)+0] += t.x; acc[(off)+1] += t.y; \
    t = __half22float2(hp2[1]); acc[(off)+2] += t.x; acc[(off)+3] += t.y; \
    t = __half22float2(hp2[2]); acc[(off)+4] += t.x; acc[(off)+5] += t.y; \
    t = __half22float2(hp2[3]); acc[(off)+6] += t.x; acc[(off)+7] += t.y; }

// ---------------------------------------------------------------------------
// Kernel 0: fp32 table -> fp16 table (one-time, 205 MB R + 102 MB W).
// ---------------------------------------------------------------------------
__global__ __launch_bounds__(256) void k_convert(const float* __restrict__ emb,
                                                 __half* __restrict__ embh) {
    const int nchunks = VROWS * (DD / 8);            // 6,400,128 chunks of 8
    const int idx = blockIdx.x * 256 + threadIdx.x;
    if (idx >= nchunks) return;
    const size_t base = (size_t)idx * 8;
    const float4 a = *(const float4*)(emb + base);
    const float4 b = *(const float4*)(emb + base + 4);
    float4 o;
    __half2* hp = (__half2*)&o;
    hp[0] = __float22half2_rn(make_float2(a.x, a.y));
    hp[1] = __float22half2_rn(make_float2(a.z, a.w));
    hp[2] = __float22half2_rn(make_float2(b.x, b.y));
    hp[3] = __float22half2_rn(make_float2(b.z, b.w));
    *(float4*)(embh + base) = o;
}

// ---------------------------------------------------------------------------
// Kernel 1: hidden[b,:] = (1/L) * sum_l embh[tok+1, :]  (fp16 rows, fp32 acc)
// Grid 256, 16 waves; wave sums 32 rows in 4-row batches (8x16B in flight).
// Lane owns 16 d's: [lane*8, lane*8+8) and [512+lane*8, ...+8).
// __launch_bounds__(1024,4): VGPR cap 128 -> no spill (round-3 lesson).
// ---------------------------------------------------------------------------
__global__ __launch_bounds__(1024, 4) void k_hidden(const int* __restrict__ tokens,
                                                    const __half* __restrict__ embh,
                                                    float* __restrict__ hidden) {
    __shared__ int   toks[LL];
    __shared__ float part[NW][DD];   // 64 KB

    const int b    = blockIdx.x;
    const int tid  = threadIdx.x;
    const int w    = tid >> 6;
    const int lane = tid & 63;
    const int o0   = lane * 8;
    const int o1   = 512 + lane * 8;

    if (tid < LL) toks[tid] = (tokens[b * LL + tid] + 1) * DD;
    __syncthreads();

    float acc[16];
    #pragma unroll
    for (int j = 0; j < 16; ++j) acc[j] = 0.f;

    for (int i = 0; i < 32; i += 4) {
        const __half* r0 = embh + toks[w * 32 + i + 0];
        const __half* r1 = embh + toks[w * 32 + i + 1];
        const __half* r2 = embh + toks[w * 32 + i + 2];
        const __half* r3 = embh + toks[w * 32 + i + 3];
        const float4 a00 = *(const float4*)(r0 + o0);
        const float4 a01 = *(const float4*)(r0 + o1);
        const float4 a10 = *(const float4*)(r1 + o0);
        const float4 a11 = *(const float4*)(r1 + o1);
        const float4 a20 = *(const float4*)(r2 + o0);
        const float4 a21 = *(const float4*)(r2 + o1);
        const float4 a30 = *(const float4*)(r3 + o0);
        const float4 a31 = *(const float4*)(r3 + o1);
        CVT8ADD(acc, 0, a00); CVT8ADD(acc, 8, a01);
        CVT8ADD(acc, 0, a10); CVT8ADD(acc, 8, a11);
        CVT8ADD(acc, 0, a20); CVT8ADD(acc, 8, a21);
        CVT8ADD(acc, 0, a30); CVT8ADD(acc, 8, a31);
    }

    *(float4*)(&part[w][o0    ]) = make_float4(acc[0],  acc[1],  acc[2],  acc[3]);
    *(float4*)(&part[w][o0 + 4]) = make_float4(acc[4],  acc[5],  acc[6],  acc[7]);
    *(float4*)(&part[w][o1    ]) = make_float4(acc[8],  acc[9],  acc[10], acc[11]);
    *(float4*)(&part[w][o1 + 4]) = make_float4(acc[12], acc[13], acc[14], acc[15]);
    __syncthreads();

    float s = 0.f;
    #pragma unroll
    for (int j = 0; j < NW; ++j) s += part[j][tid];
    hidden[b * DD + tid] = s * (1.0f / (float)LL);
}

// ---------------------------------------------------------------------------
// Kernel 2: q[b,d] = sum_e W[d,e] * hidden[b,e]   (fp32, proven round-0 form)
// grid (16, 64), 256 threads; 4 docs/block amortize W reads (L2-hot).
// ---------------------------------------------------------------------------
__global__ __launch_bounds__(256) void k_q(const float* __restrict__ hidden,
                                           const float* __restrict__ W,
                                           float* __restrict__ q) {
    __shared__ float hs[4][DD];
    const int dt  = blockIdx.x;
    const int bt  = blockIdx.y;
    const int tid = threadIdx.x;

    #pragma unroll
    for (int j = 0; j < 4; ++j)
        #pragma unroll
        for (int k = 0; k < 4; ++k)
            hs[j][k * 256 + tid] = hidden[(bt * 4 + j) * DD + k * 256 + tid];
    __syncthreads();

    const int w = tid >> 6, lane = tid & 63;

    for (int i = 0; i < 16; ++i) {
        const int d = dt * 64 + w * 16 + i;
        float a0 = 0.f, a1 = 0.f, a2 = 0.f, a3 = 0.f;
        #pragma unroll
        for (int k = 0; k < 4; ++k) {
            const int off = k * 256 + lane * 4;
            const float4 wv = *(const float4*)(W + (size_t)d * DD + off);
            const float4 h0 = *(const float4*)(&hs[0][off]);
            const float4 h1 = *(const float4*)(&hs[1][off]);
            const float4 h2 = *(const float4*)(&hs[2][off]);
            const float4 h3 = *(const float4*)(&hs[3][off]);
            a0 += wv.x * h0.x + wv.y * h0.y + wv.z * h0.z + wv.w * h0.w;
            a1 += wv.x * h1.x + wv.y * h1.y + wv.z * h1.z + wv.w * h1.w;
            a2 += wv.x * h2.x + wv.y * h2.y + wv.z * h2.z + wv.w * h2.w;
            a3 += wv.x * h3.x + wv.y * h3.y + wv.z * h3.z + wv.w * h3.w;
        }
        #pragma unroll
        for (int m = 32; m; m >>= 1) {
            a0 += __shfl_xor(a0, m, 64);
            a1 += __shfl_xor(a1, m, 64);
            a2 += __shfl_xor(a2, m, 64);
            a3 += __shfl_xor(a3, m, 64);
        }
        if (lane == 0) {
            q[(bt * 4 + 0) * DD + d] = a0;
            q[(bt * 4 + 1) * DD + d] = a1;
            q[(bt * 4 + 2) * DD + d] = a2;
            q[(bt * 4 + 3) * DD + d] = a3;
        }
    }
}

// ---------------------------------------------------------------------------
// Kernel 3: scores -> online softmax -> ct, fp16 rows / fp32 math.
// Grid 256, 16 waves x 32 rows, 2-row batch (one rescale per pair).
// VGPR budget ~90 under the 128 cap from __launch_bounds__(1024,4).
// ---------------------------------------------------------------------------
__global__ __launch_bounds__(1024, 4) void k_attn(const int* __restrict__ tokens,
                                                  const __half* __restrict__ embh,
                                                  const float* __restrict__ q,
                                                  float* __restrict__ out) {
    __shared__ int   toks[LL];
    __shared__ float ctp[NW][DD];   // 64 KB
    __shared__ float mw[NW], sw[NW];

    const int b    = blockIdx.x;
    const int tid  = threadIdx.x;
    const int w    = tid >> 6;
    const int lane = tid & 63;
    const int o0   = lane * 8;
    const int o1   = 512 + lane * 8;

    if (tid < LL) toks[tid] = (tokens[b * LL + tid] + 1) * DD;
    __syncthreads();

    float qa[16];
    {
        const float4 q00 = *(const float4*)(q + b * DD + o0);
        const float4 q01 = *(const float4*)(q + b * DD + o0 + 4);
        const float4 q10 = *(const float4*)(q + b * DD + o1);
        const float4 q11 = *(const float4*)(q + b * DD + o1 + 4);
        qa[0]=q00.x; qa[1]=q00.y; qa[2]=q00.z; qa[3]=q00.w;
        qa[4]=q01.x; qa[5]=q01.y; qa[6]=q01.z; qa[7]=q01.w;
        qa[8]=q10.x; qa[9]=q10.y; qa[10]=q10.z; qa[11]=q10.w;
        qa[12]=q11.x; qa[13]=q11.y; qa[14]=q11.z; qa[15]=q11.w;
    }

    float m = -1e30f, s = 0.f;
    float ct[16];
    #pragma unroll
    for (int j = 0; j < 16; ++j) ct[j] = 0.f;

    for (int i = 0; i < 32; i += 2) {
        const __half* ra = embh + toks[w * 32 + i    ];
        const __half* rb = embh + toks[w * 32 + i + 1];
        const float4 va0 = *(const float4*)(ra + o0);
        const float4 va1 = *(const float4*)(ra + o1);
        const float4 vb0 = *(const float4*)(rb + o0);
        const float4 vb1 = *(const float4*)(rb + o1);

        float ea[16], eb[16];
        CVT8(ea, 0, va0); CVT8(ea, 8, va1);
        CVT8(eb, 0, vb0); CVT8(eb, 8, vb1);

        float p0 = 0.f, p1 = 0.f;
        #pragma unroll
        for (int j = 0; j < 16; ++j) { p0 += ea[j] * qa[j]; p1 += eb[j] * qa[j]; }
        #pragma unroll
        for (int mm = 32; mm; mm >>= 1) {
            p0 += __shfl_xor(p0, mm, 64);
            p1 += __shfl_xor(p1, mm, 64);
        }

        const float nm = fmaxf(m, fmaxf(p0, p1));
        const float f  = __expf(m - nm);
        const float w0 = __expf(p0 - nm);
        const float w1 = __expf(p1 - nm);
        s = s * f + w0 + w1;
        #pragma unroll
        for (int j = 0; j < 16; ++j) ct[j] = ct[j] * f + w0 * ea[j] + w1 * eb[j];
        m = nm;
    }

    *(float4*)(&ctp[w][o0    ]) = make_float4(ct[0],  ct[1],  ct[2],  ct[3]);
    *(float4*)(&ctp[w][o0 + 4]) = make_float4(ct[4],  ct[5],  ct[6],  ct[7]);
    *(float4*)(&ctp[w][o1    ]) = make_float4(ct[8],  ct[9],  ct[10], ct[11]);
    *(float4*)(&ctp[w][o1 + 4]) = make_float4(ct[12], ct[13], ct[14], ct[15]);
    if (lane == 0) { mw[w] = m; sw[w] = s; }
    __syncthreads();

    float M = -1e30f;
    #pragma unroll
    for (int j = 0; j < NW; ++j) M = fmaxf(M, mw[j]);
    float denom = 0.f, sc[NW];
    #pragma unroll
    for (int j = 0; j < NW; ++j) { sc[j] = __expf(mw[j] - M); denom += sc[j] * sw[j]; }
    const float inv = 1.0f / denom;

    float acc = 0.f;
    #pragma unroll
    for (int j = 0; j < NW; ++j) acc += sc[j] * ctp[j][tid];
    out[b * DD + tid] = acc * inv;
}

// ---------------------------------------------------------------------------
extern "C" void kernel_launch(void* const* d_in, const int* in_sizes, int n_in,
                              void* d_out, int out_size, void* d_ws, size_t ws_size,
                              hipStream_t stream) {
    const int*   tokens = (const int*)d_in[0];
    // d_in[1] = max_len (scalar), fixed to LL
    const float* emb    = (const float*)d_in[2];
    const float* W      = (const float*)d_in[3];
    float*       out    = (float*)d_out;

    float*  hidden = (float*)d_ws;                       // 1 MB
    float*  q      = hidden + BB * DD;                   // 1 MB
    __half* embh   = (__half*)(q + BB * DD);             // 50001*1024*2 B ~ 98 MB

    const int nchunks = VROWS * (DD / 8);
    k_convert<<<(nchunks + 255) / 256, 256, 0, stream>>>(emb, embh);
    k_hidden<<<BB, 1024, 0, stream>>>(tokens, embh, hidden);
    dim3 g2(DD / 64, BB / 4);
    k_q<<<g2, 256, 0, stream>>>(hidden, W, q);
    k_attn<<<BB, 1024, 0, stream>>>(tokens, embh, q, out);
}